// Round 5
// baseline (326.647 us; speedup 1.0000x reference)
//
#include <hip/hip_runtime.h>

// BDC loss: intra (cosine-decayed MSE vs gathered centers) + 0.5 * masked hinge
// on pairwise cosine sim. Pipeline:
//   memset(acc+counts) -> prep (norms, intra, fhat bf16, label histogram)
//   -> gemm_hinge (fhat @ fhat^T, triangle tiles, fused hinge+mask reduction)
//   -> finalize (n_pairs from histogram, combine terms)
// Defensive: if ws_size < needed, write sentinel -1 to out instead of
// overrunning d_ws.

typedef __attribute__((ext_vector_type(8))) short bf16x8;
typedef __attribute__((ext_vector_type(4))) float f32x4;

#define NROWS 8192
#define NDIM  1024
#define NCLS  1000

// ws layout
#define FHAT_OFF   0                       // 8192*1024*2 = 16777216 B
#define ACC_OFF    16777216                // float intra_sum, float adv_sum
#define COUNTS_OFF (ACC_OFF + 16)          // 1000 * int
#define ZERO_BYTES (16 + NCLS * 4)
#define WS_NEEDED  (COUNTS_OFF + NCLS * 4)

static __device__ __forceinline__ unsigned short f2bf(float x) {
  unsigned u = __float_as_uint(x);
  u += 0x7fffu + ((u >> 16) & 1u);   // round-to-nearest-even
  return (unsigned short)(u >> 16);
}

// ---------------- prep: one block per row ----------------
__global__ __launch_bounds__(256) void prep_kernel(
    const float* __restrict__ feat, const int* __restrict__ labels,
    const float* __restrict__ centers, unsigned short* __restrict__ fhat,
    float* __restrict__ acc, int* __restrict__ counts) {
  const int b   = blockIdx.x;
  const int tid = threadIdx.x;
  const int wave = tid >> 6, lane = tid & 63;

  const float4 f = ((const float4*)(feat + (size_t)b * NDIM))[tid];
  const int lab = labels[b];
  const float4 c = ((const float4*)(centers + (size_t)lab * NDIM))[tid];

  float ff = f.x * f.x + f.y * f.y + f.z * f.z + f.w * f.w;
  float fc = f.x * c.x + f.y * c.y + f.z * c.z + f.w * c.w;
  float cc = c.x * c.x + c.y * c.y + c.z * c.z + c.w * c.w;
  float dx = f.x - c.x, dy = f.y - c.y, dz = f.z - c.z, dw = f.w - c.w;
  float se = dx * dx + dy * dy + dz * dz + dw * dw;

  #pragma unroll
  for (int off = 32; off; off >>= 1) {
    ff += __shfl_down(ff, off, 64);
    fc += __shfl_down(fc, off, 64);
    cc += __shfl_down(cc, off, 64);
    se += __shfl_down(se, off, 64);
  }

  __shared__ float red[4][4];
  __shared__ float s_inv;
  if (lane == 0) {
    red[wave][0] = ff; red[wave][1] = fc; red[wave][2] = cc; red[wave][3] = se;
  }
  __syncthreads();
  if (tid == 0) {
    float FF = red[0][0] + red[1][0] + red[2][0] + red[3][0];
    float FC = red[0][1] + red[1][1] + red[2][1] + red[3][1];
    float CC = red[0][2] + red[1][2] + red[2][2] + red[3][2];
    float SE = red[0][3] + red[1][3] + red[2][3] + red[3][3];
    float fn = fmaxf(sqrtf(FF), 1e-8f);
    float cn = fmaxf(sqrtf(CC), 1e-8f);
    float sim = FC / (fn * cn);
    atomicAdd(&acc[0], SE * expf(-sim));   // ALPHA = 1
    atomicAdd(&counts[lab], 1);
    s_inv = 1.0f / fn;
  }
  __syncthreads();

  const float inv = s_inv;
  ushort4 o;
  o.x = f2bf(f.x * inv); o.y = f2bf(f.y * inv);
  o.z = f2bf(f.z * inv); o.w = f2bf(f.w * inv);
  ((ushort4*)(fhat + (size_t)b * NDIM))[tid] = o;
}

// ---------------- GEMM + fused hinge reduction ----------------
// 128x128 tile, BK=64, 4 waves, each wave a 64x64 quadrant (4x4 frags of
// 16x16x32 bf16). Triangle: only tj >= ti, off-diagonal doubled.
__global__ __launch_bounds__(256) void gemm_hinge_kernel(
    const unsigned short* __restrict__ fhat, const int* __restrict__ labels,
    float* __restrict__ adv_acc) {
  const int ti = blockIdx.y, tj = blockIdx.x;
  if (tj < ti) return;

  __shared__ __align__(16) unsigned short Al[128 * 64];
  __shared__ __align__(16) unsigned short Bl[128 * 64];
  __shared__ int labi[128], labj[128];
  __shared__ float rsum[4];

  const int tid  = threadIdx.x;
  const int wave = tid >> 6, lane = tid & 63;
  const int qr = wave >> 1, qc = wave & 1;     // 64x64 quadrant

  if (tid < 128) labi[tid] = labels[ti * 128 + tid];
  else           labj[tid - 128] = labels[tj * 128 + (tid - 128)];

  f32x4 acc[4][4] = {};

  // staging: thread t loads 16B; row seg*32 + t/8, col (t%8)*8 elems.
  // LDS dest linear (wave-uniform base + lane*16).
  const int srow = tid >> 3;
  const int scol = (tid & 7) * 8;
  const unsigned short* a_src0 = fhat + (size_t)(ti * 128 + srow) * NDIM + scol;
  const unsigned short* b_src0 = fhat + (size_t)(tj * 128 + srow) * NDIM + scol;

  for (int k0 = 0; k0 < NDIM; k0 += 64) {
    #pragma unroll
    for (int seg = 0; seg < 4; ++seg) {
      const unsigned short* src = a_src0 + k0 + (size_t)seg * 32 * NDIM;
      __builtin_amdgcn_global_load_lds(
          (const __attribute__((address_space(1))) void*)src,
          (__attribute__((address_space(3))) void*)&Al[seg * 2048 + wave * 512],
          16, 0, 0);
    }
    #pragma unroll
    for (int seg = 0; seg < 4; ++seg) {
      const unsigned short* src = b_src0 + k0 + (size_t)seg * 32 * NDIM;
      __builtin_amdgcn_global_load_lds(
          (const __attribute__((address_space(1))) void*)src,
          (__attribute__((address_space(3))) void*)&Bl[seg * 2048 + wave * 512],
          16, 0, 0);
    }
    __syncthreads();   // compiler emits vmcnt(0) drain before barrier

    #pragma unroll
    for (int kk = 0; kk < 2; ++kk) {
      const int lr = lane & 15;
      const int lk = kk * 32 + (lane >> 4) * 8;
      bf16x8 a[4], b[4];
      #pragma unroll
      for (int m = 0; m < 4; ++m)
        a[m] = *(const bf16x8*)&Al[(qr * 64 + m * 16 + lr) * 64 + lk];
      #pragma unroll
      for (int n = 0; n < 4; ++n)
        b[n] = *(const bf16x8*)&Bl[(qc * 64 + n * 16 + lr) * 64 + lk];
      #pragma unroll
      for (int m = 0; m < 4; ++m)
        #pragma unroll
        for (int n = 0; n < 4; ++n)
          acc[m][n] = __builtin_amdgcn_mfma_f32_16x16x32_bf16(
              a[m], b[n], acc[m][n], 0, 0, 0);
    }
    __syncthreads();   // protect LDS before next stage
  }

  // epilogue: C/D layout col=lane&15, row=(lane>>4)*4+reg (m89-verified)
  float hs = 0.f;
  const int crow = (lane >> 4) * 4;
  const int ccol = lane & 15;
  #pragma unroll
  for (int m = 0; m < 4; ++m) {
    #pragma unroll
    for (int n = 0; n < 4; ++n) {
      #pragma unroll
      for (int r = 0; r < 4; ++r) {
        const int i = qr * 64 + m * 16 + crow + r;
        const int j = qc * 64 + n * 16 + ccol;
        if (labi[i] != labj[j]) {
          hs += fmaxf(0.5f - acc[m][n][r], 0.f);
        }
      }
    }
  }
  #pragma unroll
  for (int off = 32; off; off >>= 1) hs += __shfl_down(hs, off, 64);
  if (lane == 0) rsum[wave] = hs;
  __syncthreads();
  if (tid == 0) {
    float s = rsum[0] + rsum[1] + rsum[2] + rsum[3];
    if (ti != tj) s *= 2.f;   // symmetric: count (i,j) and (j,i)
    atomicAdd(adv_acc, s);
  }
}

// ---------------- finalize ----------------
__global__ __launch_bounds__(256) void finalize_kernel(
    const float* __restrict__ acc, const int* __restrict__ counts,
    float* __restrict__ out) {
  const int tid = threadIdx.x;
  long long s = 0;
  for (int c = tid; c < NCLS; c += 256) {
    long long v = counts[c];
    s += v * v;
  }
  #pragma unroll
  for (int off = 32; off; off >>= 1) s += __shfl_down(s, off, 64);
  __shared__ long long lred[4];
  if ((tid & 63) == 0) lred[tid >> 6] = s;
  __syncthreads();
  if (tid == 0) {
    long long npairs = (long long)NROWS * NROWS - (lred[0] + lred[1] + lred[2] + lred[3]);
    if (npairs < 1) npairs = 1;
    float intra = acc[0] / (float)NROWS;
    float adv   = acc[1] / (float)npairs;
    out[0] = intra + 0.5f * adv;
  }
}

// sentinel: ws too small — diagnosable without faulting
__global__ void sentinel_kernel(float* out) {
  if (threadIdx.x == 0 && blockIdx.x == 0) out[0] = -1.0f;
}

extern "C" void kernel_launch(void* const* d_in, const int* in_sizes, int n_in,
                              void* d_out, int out_size, void* d_ws, size_t ws_size,
                              hipStream_t stream) {
  const float* feat    = (const float*)d_in[0];
  const int*   labels  = (const int*)d_in[1];
  const float* centers = (const float*)d_in[2];
  float* out = (float*)d_out;

  if (ws_size < (size_t)WS_NEEDED) {
    sentinel_kernel<<<1, 64, 0, stream>>>(out);
    return;
  }

  char* ws = (char*)d_ws;
  unsigned short* fhat = (unsigned short*)(ws + FHAT_OFF);
  float* acc   = (float*)(ws + ACC_OFF);
  int* counts  = (int*)(ws + COUNTS_OFF);

  hipMemsetAsync(ws + ACC_OFF, 0, ZERO_BYTES, stream);

  prep_kernel<<<NROWS, 256, 0, stream>>>(feat, labels, centers, fhat, acc, counts);

  dim3 grid(64, 64);
  gemm_hinge_kernel<<<grid, 256, 0, stream>>>(fhat, labels, acc + 1);

  finalize_kernel<<<1, 256, 0, stream>>>(acc, counts, out);
}

// Round 8
// 215.624 us; speedup vs baseline: 1.5149x; 1.5149x over previous
//
#include <hip/hip_runtime.h>

// BDC loss, atomic-free pipeline:
//   prep   (8192 blocks): norms, intra partial per row (plain store), fhat bf16
//   gemm   (528 triangle tiles, 256x256, 8 waves): fused hinge partial per tile
//   final  (1 block): sum partials + LDS label histogram -> n_pairs -> out
// No global atomics, no memset. R5 evidence: 8192 same-address atomicAdds in
// prep cost ~155us (L2 RMW serialization); GEMM at 128^2+2ph = 461 TF.

typedef __attribute__((ext_vector_type(8))) short bf16x8;
typedef __attribute__((ext_vector_type(4))) float f32x4;

#define NROWS 8192
#define NDIM  1024
#define NCLS  1000
#define NTILE 32                 // 256-row tiles per side
#define NTRI  528                // NTILE*(NTILE+1)/2 triangle tiles

// ws layout
#define FHAT_OFF  0                          // 8192*1024*2 = 16777216 B
#define INTRA_OFF 16777216                   // 8192 f32
#define ADV_OFF   (INTRA_OFF + NROWS * 4)    // 528 f32
#define WS_NEEDED (ADV_OFF + NTRI * 4)

static __device__ __forceinline__ unsigned short f2bf(float x) {
  unsigned u = __float_as_uint(x);
  u += 0x7fffu + ((u >> 16) & 1u);   // round-to-nearest-even
  return (unsigned short)(u >> 16);
}

// ---------------- prep: one block per row, no atomics ----------------
__global__ __launch_bounds__(256) void prep_kernel(
    const float* __restrict__ feat, const int* __restrict__ labels,
    const float* __restrict__ centers, unsigned short* __restrict__ fhat,
    float* __restrict__ intra_val) {
  const int b   = blockIdx.x;
  const int tid = threadIdx.x;
  const int wave = tid >> 6, lane = tid & 63;

  const float4 f = ((const float4*)(feat + (size_t)b * NDIM))[tid];
  const int lab = labels[b];
  const float4 c = ((const float4*)(centers + (size_t)lab * NDIM))[tid];

  float ff = f.x * f.x + f.y * f.y + f.z * f.z + f.w * f.w;
  float fc = f.x * c.x + f.y * c.y + f.z * c.z + f.w * c.w;
  float cc = c.x * c.x + c.y * c.y + c.z * c.z + c.w * c.w;
  float dx = f.x - c.x, dy = f.y - c.y, dz = f.z - c.z, dw = f.w - c.w;
  float se = dx * dx + dy * dy + dz * dz + dw * dw;

  #pragma unroll
  for (int off = 32; off; off >>= 1) {
    ff += __shfl_down(ff, off, 64);
    fc += __shfl_down(fc, off, 64);
    cc += __shfl_down(cc, off, 64);
    se += __shfl_down(se, off, 64);
  }

  __shared__ float red[4][4];
  __shared__ float s_inv;
  if (lane == 0) {
    red[wave][0] = ff; red[wave][1] = fc; red[wave][2] = cc; red[wave][3] = se;
  }
  __syncthreads();
  if (tid == 0) {
    float FF = red[0][0] + red[1][0] + red[2][0] + red[3][0];
    float FC = red[0][1] + red[1][1] + red[2][1] + red[3][1];
    float CC = red[0][2] + red[1][2] + red[2][2] + red[3][2];
    float SE = red[0][3] + red[1][3] + red[2][3] + red[3][3];
    float fn = fmaxf(sqrtf(FF), 1e-8f);
    float cn = fmaxf(sqrtf(CC), 1e-8f);
    float sim = FC / (fn * cn);
    intra_val[b] = SE * expf(-sim);   // ALPHA = 1; plain store, no atomic
    s_inv = 1.0f / fn;
  }
  __syncthreads();

  const float inv = s_inv;
  ushort4 o;
  o.x = f2bf(f.x * inv); o.y = f2bf(f.y * inv);
  o.z = f2bf(f.z * inv); o.w = f2bf(f.w * inv);
  ((ushort4*)(fhat + (size_t)b * NDIM))[tid] = o;
}

// ---------------- GEMM + fused hinge ----------------
// 256x256 tile, BK=64, 8 waves (2Mx4N), each wave 128x64 (8x4 frags of
// 16x16x32 bf16). 1D triangle grid: bid -> (ti,tj), ti<=tj; off-diag doubled.
#define CUMUL(r) ((r) * NTILE - (r) * ((r) - 1) / 2)

__global__ __launch_bounds__(512) void gemm_hinge_kernel(
    const unsigned short* __restrict__ fhat, const int* __restrict__ labels,
    float* __restrict__ adv_val) {
  const int bid = blockIdx.x;
  // triangle decode (row-major upper triangle), float solve + exact fixup
  const float nf = (float)NTILE + 0.5f;
  int ti = (int)floorf(nf - sqrtf(nf * nf - 2.0f * (float)bid));
  while (ti > 0 && bid < CUMUL(ti)) --ti;
  while (bid >= CUMUL(ti + 1)) ++ti;
  const int tj = ti + (bid - CUMUL(ti));

  __shared__ __align__(16) unsigned short Al[256 * 64];  // 32 KB
  __shared__ __align__(16) unsigned short Bl[256 * 64];  // 32 KB
  __shared__ int labi[256], labj[256];
  __shared__ float rsum[8];

  const int tid  = threadIdx.x;
  const int wave = tid >> 6, lane = tid & 63;
  const int wr = wave >> 2, wc = wave & 3;   // 2x4 wave grid -> 128x64 each

  if (tid < 256) labi[tid] = labels[ti * 256 + tid];
  else           labj[tid - 256] = labels[tj * 256 + (tid - 256)];

  f32x4 acc[8][4] = {};

  // staging: thread t -> row s*64 + t/8, col (t%8)*8; LDS dest linear
  // (wave-uniform base + lane*16B), elem off = s*4096 + wave*512 + lane*8.
  const int srow = tid >> 3;
  const int scol = (tid & 7) * 8;
  const unsigned short* a0 = fhat + (size_t)(ti * 256 + srow) * NDIM + scol;
  const unsigned short* b0 = fhat + (size_t)(tj * 256 + srow) * NDIM + scol;

  for (int k0 = 0; k0 < NDIM; k0 += 64) {
    #pragma unroll
    for (int s = 0; s < 4; ++s)
      __builtin_amdgcn_global_load_lds(
          (const __attribute__((address_space(1))) void*)(a0 + k0 + (size_t)s * 64 * NDIM),
          (__attribute__((address_space(3))) void*)&Al[s * 4096 + wave * 512],
          16, 0, 0);
    #pragma unroll
    for (int s = 0; s < 4; ++s)
      __builtin_amdgcn_global_load_lds(
          (const __attribute__((address_space(1))) void*)(b0 + k0 + (size_t)s * 64 * NDIM),
          (__attribute__((address_space(3))) void*)&Bl[s * 4096 + wave * 512],
          16, 0, 0);
    __syncthreads();   // compiler drains vmcnt before barrier

    #pragma unroll
    for (int kk = 0; kk < 2; ++kk) {
      const int lr = lane & 15;
      const int lk = kk * 32 + (lane >> 4) * 8;
      bf16x8 a[8], b[4];
      #pragma unroll
      for (int m = 0; m < 8; ++m)
        a[m] = *(const bf16x8*)&Al[(wr * 128 + m * 16 + lr) * 64 + lk];
      #pragma unroll
      for (int n = 0; n < 4; ++n)
        b[n] = *(const bf16x8*)&Bl[(wc * 64 + n * 16 + lr) * 64 + lk];
      #pragma unroll
      for (int m = 0; m < 8; ++m)
        #pragma unroll
        for (int n = 0; n < 4; ++n)
          acc[m][n] = __builtin_amdgcn_mfma_f32_16x16x32_bf16(
              a[m], b[n], acc[m][n], 0, 0, 0);
    }
    __syncthreads();
  }

  // epilogue: C/D layout col=lane&15, row=(lane>>4)*4+reg (m89-verified)
  float hs = 0.f;
  const int crow = (lane >> 4) * 4;
  const int ccol = lane & 15;
  #pragma unroll
  for (int m = 0; m < 8; ++m) {
    #pragma unroll
    for (int n = 0; n < 4; ++n) {
      #pragma unroll
      for (int r = 0; r < 4; ++r) {
        const int i = wr * 128 + m * 16 + crow + r;
        const int j = wc * 64 + n * 16 + ccol;
        if (labi[i] != labj[j]) {
          hs += fmaxf(0.5f - acc[m][n][r], 0.f);
        }
      }
    }
  }
  #pragma unroll
  for (int off = 32; off; off >>= 1) hs += __shfl_down(hs, off, 64);
  if (lane == 0) rsum[wave] = hs;
  __syncthreads();
  if (tid == 0) {
    float s = 0.f;
    #pragma unroll
    for (int w = 0; w < 8; ++w) s += rsum[w];
    if (ti != tj) s *= 2.f;       // symmetric: (i,j) and (j,i)
    adv_val[bid] = s;             // plain store, no atomic
  }
}

// ---------------- finalize: sums + label histogram -> out ----------------
__global__ __launch_bounds__(1024) void finalize_kernel(
    const float* __restrict__ intra_val, const float* __restrict__ adv_val,
    const int* __restrict__ labels, float* __restrict__ out) {
  __shared__ int hist[NCLS];
  __shared__ float rsi[16], rsa[16];
  __shared__ int rsq[16];
  const int tid = threadIdx.x;
  const int wave = tid >> 6, lane = tid & 63;

  for (int c = tid; c < NCLS; c += 1024) hist[c] = 0;
  __syncthreads();
  for (int i = tid; i < NROWS; i += 1024) atomicAdd(&hist[labels[i]], 1);

  float si = 0.f;
  for (int i = tid; i < NROWS; i += 1024) si += intra_val[i];
  float sa = 0.f;
  for (int i = tid; i < NTRI; i += 1024) sa += adv_val[i];
  __syncthreads();
  int sq = 0;
  for (int c = tid; c < NCLS; c += 1024) sq += hist[c] * hist[c];

  #pragma unroll
  for (int off = 32; off; off >>= 1) {
    si += __shfl_down(si, off, 64);
    sa += __shfl_down(sa, off, 64);
    sq += __shfl_down(sq, off, 64);
  }
  if (lane == 0) { rsi[wave] = si; rsa[wave] = sa; rsq[wave] = sq; }
  __syncthreads();
  if (tid == 0) {
    float SI = 0.f, SA = 0.f; long long SQ = 0;
    for (int w = 0; w < 16; ++w) { SI += rsi[w]; SA += rsa[w]; SQ += rsq[w]; }
    long long npairs = (long long)NROWS * NROWS - SQ;
    if (npairs < 1) npairs = 1;
    out[0] = SI / (float)NROWS + 0.5f * (SA / (float)npairs);
  }
}

// sentinel: ws too small — diagnosable without faulting
__global__ void sentinel_kernel(float* out) {
  if (threadIdx.x == 0 && blockIdx.x == 0) out[0] = -1.0f;
}

extern "C" void kernel_launch(void* const* d_in, const int* in_sizes, int n_in,
                              void* d_out, int out_size, void* d_ws, size_t ws_size,
                              hipStream_t stream) {
  const float* feat    = (const float*)d_in[0];
  const int*   labels  = (const int*)d_in[1];
  const float* centers = (const float*)d_in[2];
  float* out = (float*)d_out;

  if (ws_size < (size_t)WS_NEEDED) {
    sentinel_kernel<<<1, 64, 0, stream>>>(out);
    return;
  }

  char* ws = (char*)d_ws;
  unsigned short* fhat = (unsigned short*)(ws + FHAT_OFF);
  float* intra_val = (float*)(ws + INTRA_OFF);
  float* adv_val   = (float*)(ws + ADV_OFF);

  prep_kernel<<<NROWS, 256, 0, stream>>>(feat, labels, centers, fhat, intra_val);
  gemm_hinge_kernel<<<NTRI, 512, 0, stream>>>(fhat, labels, adv_val);
  finalize_kernel<<<1, 1024, 0, stream>>>(intra_val, adv_val, labels, out);
}

// Round 9
// 204.901 us; speedup vs baseline: 1.5942x; 1.0523x over previous
//
#include <hip/hip_runtime.h>

// BDC loss, round 9.
//   prep   (2048 blocks, 1 wave/row): norms+intra+fhat, barrier-free; hist via
//          spread global atomics (1000 addrs, ~8 ops each)
//   gemm   (528 triangle tiles, 256x256, BK=32 double-buffered prefetch,
//          1 barrier/K-tile, XCD-chunk swizzle)
//   final  (1 block): sum partials + hist^2 -> n_pairs -> out
// R8 evidence: gemm 137us @ MfmaUtil 21% (2ph stage-stall); prep+finalize ~78us
// (latency-serialized micro-blocks).

typedef __attribute__((ext_vector_type(8))) short bf16x8;
typedef __attribute__((ext_vector_type(4))) float f32x4;

#define NROWS 8192
#define NDIM  1024
#define NCLS  1000
#define NTILE 32                 // 256-row tiles per side
#define NTRI  528                // NTILE*(NTILE+1)/2 = 8 * 66

// ws layout
#define FHAT_OFF  0                          // 8192*1024*2 = 16777216 B
#define INTRA_OFF 16777216                   // 8192 f32
#define ADV_OFF   (INTRA_OFF + NROWS * 4)    // 528 f32
#define HIST_OFF  (ADV_OFF + NTRI * 4)       // 1000 int
#define WS_NEEDED (HIST_OFF + NCLS * 4)

static __device__ __forceinline__ unsigned short f2bf(float x) {
  unsigned u = __float_as_uint(x);
  u += 0x7fffu + ((u >> 16) & 1u);   // round-to-nearest-even
  return (unsigned short)(u >> 16);
}

// ---------------- prep: one wave per row, no barriers, no LDS ----------------
__global__ __launch_bounds__(256) void prep_kernel(
    const float* __restrict__ feat, const int* __restrict__ labels,
    const float* __restrict__ centers, unsigned short* __restrict__ fhat,
    float* __restrict__ intra_val, int* __restrict__ hist) {
  const int tid = threadIdx.x, wave = tid >> 6, lane = tid & 63;
  const int row = blockIdx.x * 4 + wave;

  const float4* fr = (const float4*)(feat + (size_t)row * NDIM);
  const int lab = labels[row];
  const float4* cr = (const float4*)(centers + (size_t)lab * NDIM);

  float4 f[4], c[4];
  #pragma unroll
  for (int j = 0; j < 4; ++j) { f[j] = fr[lane + j * 64]; c[j] = cr[lane + j * 64]; }

  float ff = 0.f, fc = 0.f, cc = 0.f, se = 0.f;
  #pragma unroll
  for (int j = 0; j < 4; ++j) {
    ff += f[j].x*f[j].x + f[j].y*f[j].y + f[j].z*f[j].z + f[j].w*f[j].w;
    fc += f[j].x*c[j].x + f[j].y*c[j].y + f[j].z*c[j].z + f[j].w*c[j].w;
    cc += c[j].x*c[j].x + c[j].y*c[j].y + c[j].z*c[j].z + c[j].w*c[j].w;
    float dx = f[j].x-c[j].x, dy = f[j].y-c[j].y, dz = f[j].z-c[j].z, dw = f[j].w-c[j].w;
    se += dx*dx + dy*dy + dz*dz + dw*dw;
  }

  #pragma unroll
  for (int off = 1; off < 64; off <<= 1) {   // butterfly: all lanes get totals
    ff += __shfl_xor(ff, off, 64);
    fc += __shfl_xor(fc, off, 64);
    cc += __shfl_xor(cc, off, 64);
    se += __shfl_xor(se, off, 64);
  }

  const float fn = fmaxf(sqrtf(ff), 1e-8f);
  const float cn = fmaxf(sqrtf(cc), 1e-8f);
  const float inv = 1.0f / fn;
  if (lane == 0) {
    intra_val[row] = se * expf(-(fc / (fn * cn)));   // ALPHA = 1
    atomicAdd(&hist[lab], 1);                        // ~8 ops per address
  }

  ushort4* orow = (ushort4*)(fhat + (size_t)row * NDIM);
  #pragma unroll
  for (int j = 0; j < 4; ++j) {
    ushort4 o;
    o.x = f2bf(f[j].x * inv); o.y = f2bf(f[j].y * inv);
    o.z = f2bf(f[j].z * inv); o.w = f2bf(f[j].w * inv);
    orow[lane + j * 64] = o;
  }
}

// ---------------- GEMM + fused hinge ----------------
// 256x256 tile, BK=32 double-buffered, 8 waves (2Mx4N), per-wave 128x64
// (8x4 frags of 16x16x32). Prefetch tile t+1 before computing tile t;
// single __syncthreads per tile (its vmcnt/lgkmcnt drain covers both
// buffer-publish and buffer-reuse). LDS 64KB -> 2 blocks/CU.
#define CUMUL(r) ((r) * NTILE - (r) * ((r) - 1) / 2)

__global__ __launch_bounds__(512) void gemm_hinge_kernel(
    const unsigned short* __restrict__ fhat, const int* __restrict__ labels,
    float* __restrict__ adv_val) {
  const int bid0 = blockIdx.x;
  const int bid  = (bid0 & 7) * 66 + (bid0 >> 3);   // XCD chunk swizzle, 528=8*66
  const float nf = (float)NTILE + 0.5f;
  int ti = (int)floorf(nf - sqrtf(nf * nf - 2.0f * (float)bid));
  while (ti > 0 && bid < CUMUL(ti)) --ti;
  while (bid >= CUMUL(ti + 1)) ++ti;
  const int tj = ti + (bid - CUMUL(ti));

  __shared__ __align__(16) unsigned short Al[2][256 * 32];  // 2 x 16KB
  __shared__ __align__(16) unsigned short Bl[2][256 * 32];  // 2 x 16KB
  __shared__ int labi[256], labj[256];
  __shared__ float rsum[8];

  const int tid  = threadIdx.x;
  const int wave = tid >> 6, lane = tid & 63;
  const int wr = wave >> 2, wc = wave & 3;   // 2x4 wave grid -> 128x64 each

  if (tid < 256) labi[tid] = labels[ti * 256 + tid];
  else           labj[tid - 256] = labels[tj * 256 + (tid - 256)];

  f32x4 acc[8][4] = {};

  // staging: thread t, half l in {0,1}: row = l*128 + t/4, col = (t%4)*8.
  // LDS elem = l*4096 + t*8 (linear: wave-uniform base + lane*16B).
  const int srow = tid >> 2;          // 0..127
  const int scol = (tid & 3) * 8;     // 0,8,16,24
  const unsigned short* a0 = fhat + (size_t)(ti * 256 + srow) * NDIM + scol;
  const unsigned short* b0 = fhat + (size_t)(tj * 256 + srow) * NDIM + scol;

#define STAGE(buf, k0)                                                        \
  do {                                                                        \
    _Pragma("unroll")                                                         \
    for (int l = 0; l < 2; ++l) {                                             \
      __builtin_amdgcn_global_load_lds(                                       \
          (const __attribute__((address_space(1))) void*)(a0 + (k0) +         \
              (size_t)l * 128 * NDIM),                                        \
          (__attribute__((address_space(3))) void*)&Al[buf][l * 4096 + wave * 512], \
          16, 0, 0);                                                          \
      __builtin_amdgcn_global_load_lds(                                       \
          (const __attribute__((address_space(1))) void*)(b0 + (k0) +         \
              (size_t)l * 128 * NDIM),                                        \
          (__attribute__((address_space(3))) void*)&Bl[buf][l * 4096 + wave * 512], \
          16, 0, 0);                                                          \
    }                                                                         \
  } while (0)

#define COMPUTE(buf)                                                          \
  do {                                                                        \
    const int lr = lane & 15;                                                 \
    const int lk = (lane >> 4) * 8;                                           \
    bf16x8 a[8], b[4];                                                        \
    _Pragma("unroll")                                                         \
    for (int m = 0; m < 8; ++m)                                               \
      a[m] = *(const bf16x8*)&Al[buf][(wr * 128 + m * 16 + lr) * 32 + lk];    \
    _Pragma("unroll")                                                         \
    for (int n = 0; n < 4; ++n)                                               \
      b[n] = *(const bf16x8*)&Bl[buf][(wc * 64 + n * 16 + lr) * 32 + lk];     \
    _Pragma("unroll")                                                         \
    for (int m = 0; m < 8; ++m)                                               \
      _Pragma("unroll")                                                       \
      for (int n = 0; n < 4; ++n)                                             \
        acc[m][n] = __builtin_amdgcn_mfma_f32_16x16x32_bf16(                  \
            a[m], b[n], acc[m][n], 0, 0, 0);                                  \
  } while (0)

  STAGE(0, 0);
  __syncthreads();                     // publish tile 0
  for (int t = 0; t < 31; ++t) {
    const int cur = t & 1;
    STAGE(cur ^ 1, (t + 1) * 32);      // prefetch next tile (other buffer)
    COMPUTE(cur);                      // MFMA on current tile
    __syncthreads();                   // drain vmcnt (publish) + join (reuse)
  }
  COMPUTE(1);                          // tile 31, no prefetch

#undef STAGE
#undef COMPUTE

  // epilogue: C/D layout col=lane&15, row=(lane>>4)*4+reg (m89-verified)
  float hs = 0.f;
  const int crow = (lane >> 4) * 4;
  const int ccol = lane & 15;
  #pragma unroll
  for (int m = 0; m < 8; ++m) {
    #pragma unroll
    for (int n = 0; n < 4; ++n) {
      #pragma unroll
      for (int r = 0; r < 4; ++r) {
        const int i = wr * 128 + m * 16 + crow + r;
        const int j = wc * 64 + n * 16 + ccol;
        if (labi[i] != labj[j]) {
          hs += fmaxf(0.5f - acc[m][n][r], 0.f);
        }
      }
    }
  }
  #pragma unroll
  for (int off = 32; off; off >>= 1) hs += __shfl_down(hs, off, 64);
  if (lane == 0) rsum[wave] = hs;
  __syncthreads();
  if (tid == 0) {
    float s = 0.f;
    #pragma unroll
    for (int w = 0; w < 8; ++w) s += rsum[w];
    if (ti != tj) s *= 2.f;       // symmetric: (i,j) and (j,i)
    adv_val[bid0] = s;            // plain store
  }
}

// ---------------- finalize ----------------
__global__ __launch_bounds__(1024) void finalize_kernel(
    const float* __restrict__ intra_val, const float* __restrict__ adv_val,
    const int* __restrict__ hist, float* __restrict__ out) {
  __shared__ float rsi[16], rsa[16];
  __shared__ long long rsq[16];
  const int tid = threadIdx.x;
  const int wave = tid >> 6, lane = tid & 63;

  float si = 0.f;
  for (int i = tid; i < NROWS; i += 1024) si += intra_val[i];
  float sa = 0.f;
  if (tid < NTRI) sa = adv_val[tid];
  long long sq = 0;
  if (tid < NCLS) { long long h = hist[tid]; sq = h * h; }

  #pragma unroll
  for (int off = 32; off; off >>= 1) {
    si += __shfl_down(si, off, 64);
    sa += __shfl_down(sa, off, 64);
    sq += __shfl_down(sq, off, 64);
  }
  if (lane == 0) { rsi[wave] = si; rsa[wave] = sa; rsq[wave] = sq; }
  __syncthreads();
  if (tid == 0) {
    float SI = 0.f, SA = 0.f; long long SQ = 0;
    for (int w = 0; w < 16; ++w) { SI += rsi[w]; SA += rsa[w]; SQ += rsq[w]; }
    long long npairs = (long long)NROWS * NROWS - SQ;
    if (npairs < 1) npairs = 1;
    out[0] = SI / (float)NROWS + 0.5f * (SA / (float)npairs);
  }
}

// sentinel: ws too small — diagnosable without faulting
__global__ void sentinel_kernel(float* out) {
  if (threadIdx.x == 0 && blockIdx.x == 0) out[0] = -1.0f;
}

extern "C" void kernel_launch(void* const* d_in, const int* in_sizes, int n_in,
                              void* d_out, int out_size, void* d_ws, size_t ws_size,
                              hipStream_t stream) {
  const float* feat    = (const float*)d_in[0];
  const int*   labels  = (const int*)d_in[1];
  const float* centers = (const float*)d_in[2];
  float* out = (float*)d_out;

  if (ws_size < (size_t)WS_NEEDED) {
    sentinel_kernel<<<1, 64, 0, stream>>>(out);
    return;
  }

  char* ws = (char*)d_ws;
  unsigned short* fhat = (unsigned short*)(ws + FHAT_OFF);
  float* intra_val = (float*)(ws + INTRA_OFF);
  float* adv_val   = (float*)(ws + ADV_OFF);
  int*   hist      = (int*)(ws + HIST_OFF);

  hipMemsetAsync(ws + HIST_OFF, 0, NCLS * 4, stream);

  prep_kernel<<<NROWS / 4, 256, 0, stream>>>(feat, labels, centers, fhat,
                                             intra_val, hist);
  gemm_hinge_kernel<<<NTRI, 512, 0, stream>>>(fhat, labels, adv_val);
  finalize_kernel<<<1, 1024, 0, stream>>>(intra_val, adv_val, hist, out);
}

// Round 11
// 181.996 us; speedup vs baseline: 1.7948x; 1.1259x over previous
//
#include <hip/hip_runtime.h>

// BDC loss, round 11 (= round-10 kernel, never ran due to infra; re-audited).
//   prep   (2048 blocks, 1 wave/row): norms+intra+fhat
//   gemm   (528 triangle tiles, 256x256, 8 waves): counted-vmcnt dbuf K-loop
//          (raw s_barrier, vmcnt(8) never 0) + XOR bank swizzle both-sides
//   final  (1 block)
// R9 evidence: 1 blk/CU (88 VGPR + 128 acc), __syncthreads vmcnt(0) drain =
// 2-phase stall, MfmaUtil 22%, bank conflicts 6.5e6. This round: T4 + T2.

typedef __attribute__((ext_vector_type(8))) short bf16x8;
typedef __attribute__((ext_vector_type(4))) float f32x4;

#define NROWS 8192
#define NDIM  1024
#define NCLS  1000
#define NTILE 32
#define NTRI  528                // 32*33/2 = 8 * 66

#define FHAT_OFF  0                          // 16777216 B
#define INTRA_OFF 16777216                   // 8192 f32
#define ADV_OFF   (INTRA_OFF + NROWS * 4)    // 528 f32
#define HIST_OFF  (ADV_OFF + NTRI * 4)       // 1000 int
#define WS_NEEDED (HIST_OFF + NCLS * 4)

static __device__ __forceinline__ unsigned short f2bf(float x) {
  unsigned u = __float_as_uint(x);
  u += 0x7fffu + ((u >> 16) & 1u);
  return (unsigned short)(u >> 16);
}

// ---------------- prep (unchanged from R9) ----------------
__global__ __launch_bounds__(256) void prep_kernel(
    const float* __restrict__ feat, const int* __restrict__ labels,
    const float* __restrict__ centers, unsigned short* __restrict__ fhat,
    float* __restrict__ intra_val, int* __restrict__ hist) {
  const int tid = threadIdx.x, wave = tid >> 6, lane = tid & 63;
  const int row = blockIdx.x * 4 + wave;

  const float4* fr = (const float4*)(feat + (size_t)row * NDIM);
  const int lab = labels[row];
  const float4* cr = (const float4*)(centers + (size_t)lab * NDIM);

  float4 f[4], c[4];
  #pragma unroll
  for (int j = 0; j < 4; ++j) { f[j] = fr[lane + j * 64]; c[j] = cr[lane + j * 64]; }

  float ff = 0.f, fc = 0.f, cc = 0.f, se = 0.f;
  #pragma unroll
  for (int j = 0; j < 4; ++j) {
    ff += f[j].x*f[j].x + f[j].y*f[j].y + f[j].z*f[j].z + f[j].w*f[j].w;
    fc += f[j].x*c[j].x + f[j].y*c[j].y + f[j].z*c[j].z + f[j].w*c[j].w;
    cc += c[j].x*c[j].x + c[j].y*c[j].y + c[j].z*c[j].z + c[j].w*c[j].w;
    float dx = f[j].x-c[j].x, dy = f[j].y-c[j].y, dz = f[j].z-c[j].z, dw = f[j].w-c[j].w;
    se += dx*dx + dy*dy + dz*dz + dw*dw;
  }
  #pragma unroll
  for (int off = 1; off < 64; off <<= 1) {
    ff += __shfl_xor(ff, off, 64);
    fc += __shfl_xor(fc, off, 64);
    cc += __shfl_xor(cc, off, 64);
    se += __shfl_xor(se, off, 64);
  }
  const float fn = fmaxf(sqrtf(ff), 1e-8f);
  const float cn = fmaxf(sqrtf(cc), 1e-8f);
  const float inv = 1.0f / fn;
  if (lane == 0) {
    intra_val[row] = se * expf(-(fc / (fn * cn)));
    atomicAdd(&hist[lab], 1);
  }
  ushort4* orow = (ushort4*)(fhat + (size_t)row * NDIM);
  #pragma unroll
  for (int j = 0; j < 4; ++j) {
    ushort4 o;
    o.x = f2bf(f[j].x * inv); o.y = f2bf(f[j].y * inv);
    o.z = f2bf(f[j].z * inv); o.w = f2bf(f[j].w * inv);
    orow[lane + j * 64] = o;
  }
}

// ---------------- GEMM + fused hinge, counted-vmcnt dbuf ----------------
#define CUMUL(r) ((r) * NTILE - (r) * ((r) - 1) / 2)

__global__ __launch_bounds__(512) void gemm_hinge_kernel(
    const unsigned short* __restrict__ fhat, const int* __restrict__ labels,
    float* __restrict__ adv_val) {
  const int bid0 = blockIdx.x;
  const int bid  = (bid0 & 7) * 66 + (bid0 >> 3);   // XCD chunk swizzle
  const float nf = (float)NTILE + 0.5f;
  int ti = (int)floorf(nf - sqrtf(nf * nf - 2.0f * (float)bid));
  while (ti > 0 && bid < CUMUL(ti)) --ti;
  while (bid >= CUMUL(ti + 1)) ++ti;
  const int tj = ti + (bid - CUMUL(ti));

  // swizzled LDS: elem(row,col) at row*64 + (col ^ ((row&7)<<3)), 8-elem slots
  __shared__ __align__(16) unsigned short Al[2][256 * 64];  // 2 x 32 KB
  __shared__ __align__(16) unsigned short Bl[2][256 * 64];  // 2 x 32 KB
  __shared__ int labi[256], labj[256];
  __shared__ float rsum[8];

  const int tid  = threadIdx.x;
  const int wave = tid >> 6, lane = tid & 63;
  const int wr = wave >> 2, wc = wave & 3;   // 2x4 -> per-wave 128x64

  if (tid < 256) labi[tid] = labels[ti * 256 + tid];
  else           labj[tid - 256] = labels[tj * 256 + (tid - 256)];

  f32x4 acc[8][4] = {};

  // staging: instr j of wave w writes LDS bytes [(w*4+j)*1024 .. +1024),
  // lane l at +16l -> (row=(w*4+j)*8 + l/8, slot=l%8). Source col-slot
  // pre-swizzled: (l%8) ^ (l/8)   (row&7 == l/8 on this path).
  const int l8 = lane >> 3;
  const int sl = ((lane & 7) ^ l8) * 8;              // source col offset, elems
  const unsigned short* aS = fhat + (size_t)(ti * 256 + wave * 32 + l8) * NDIM + sl;
  const unsigned short* bS = fhat + (size_t)(tj * 256 + wave * 32 + l8) * NDIM + sl;

#define STAGE(BUF, K0)                                                        \
  do {                                                                        \
    _Pragma("unroll")                                                         \
    for (int j = 0; j < 4; ++j) {                                             \
      __builtin_amdgcn_global_load_lds(                                       \
          (const __attribute__((address_space(1))) void*)(aS + (K0) + j * 8 * NDIM), \
          (__attribute__((address_space(3))) void*)&Al[BUF][(wave * 4 + j) * 512],   \
          16, 0, 0);                                                          \
      __builtin_amdgcn_global_load_lds(                                       \
          (const __attribute__((address_space(1))) void*)(bS + (K0) + j * 8 * NDIM), \
          (__attribute__((address_space(3))) void*)&Bl[BUF][(wave * 4 + j) * 512],   \
          16, 0, 0);                                                          \
    }                                                                         \
  } while (0)

  const int lr = lane & 15;
  const int hk = (lane >> 4) * 8;
  const int xr = (lr & 7) << 3;                      // read-side XOR (elems)

#define COMPUTE(BUF)                                                          \
  do {                                                                        \
    _Pragma("unroll")                                                         \
    for (int kk = 0; kk < 2; ++kk) {                                          \
      const int lk = kk * 32 + hk;                                            \
      const int lx = lk ^ xr;                                                 \
      bf16x8 a[8], b[4];                                                      \
      _Pragma("unroll")                                                       \
      for (int m = 0; m < 8; ++m)                                             \
        a[m] = *(const bf16x8*)&Al[BUF][(wr * 128 + m * 16 + lr) * 64 + lx];  \
      _Pragma("unroll")                                                       \
      for (int n = 0; n < 4; ++n)                                             \
        b[n] = *(const bf16x8*)&Bl[BUF][(wc * 64 + n * 16 + lr) * 64 + lx];   \
      _Pragma("unroll")                                                       \
      for (int m = 0; m < 8; ++m)                                             \
        _Pragma("unroll")                                                     \
        for (int n = 0; n < 4; ++n)                                           \
          acc[m][n] = __builtin_amdgcn_mfma_f32_16x16x32_bf16(                \
              a[m], b[n], acc[m][n], 0, 0, 0);                                \
    }                                                                         \
  } while (0)

// one K-tile: stage next (8 loads), wait for CURRENT tile only (8 in flight),
// raw barrier (no auto vmcnt(0)), compute, drain own lgkm, barrier (frees buf)
#define KITER(T, CBUF)                                                        \
  do {                                                                        \
    STAGE(CBUF ^ 1, ((T) + 1) * 64);                                          \
    __builtin_amdgcn_sched_barrier(0);                                        \
    asm volatile("s_waitcnt vmcnt(8)" ::: "memory");                          \
    __builtin_amdgcn_sched_barrier(0);                                        \
    __builtin_amdgcn_s_barrier();                                             \
    __builtin_amdgcn_sched_barrier(0);                                        \
    COMPUTE(CBUF);                                                            \
    asm volatile("s_waitcnt lgkmcnt(0)" ::: "memory");                        \
    __builtin_amdgcn_sched_barrier(0);                                        \
    __builtin_amdgcn_s_barrier();                                             \
    __builtin_amdgcn_sched_barrier(0);                                        \
  } while (0)

  STAGE(0, 0);                        // prologue: K-tile 0 -> buf0
  #pragma unroll 1
  for (int t2 = 0; t2 < 7; ++t2) {    // K-tiles 0..13
    KITER(2 * t2, 0);
    KITER(2 * t2 + 1, 1);
  }
  KITER(14, 0);                       // stages K-tile 15
  // tail: K-tile 15, no stage
  asm volatile("s_waitcnt vmcnt(0)" ::: "memory");
  __builtin_amdgcn_sched_barrier(0);
  __builtin_amdgcn_s_barrier();
  __builtin_amdgcn_sched_barrier(0);
  COMPUTE(1);

#undef KITER
#undef STAGE
#undef COMPUTE

  // epilogue: C/D col=lane&15, row=(lane>>4)*4+reg (m89-verified)
  float hs = 0.f;
  const int crow = (lane >> 4) * 4;
  const int ccol = lane & 15;
  #pragma unroll
  for (int m = 0; m < 8; ++m) {
    #pragma unroll
    for (int n = 0; n < 4; ++n) {
      #pragma unroll
      for (int r = 0; r < 4; ++r) {
        const int i = wr * 128 + m * 16 + crow + r;
        const int j = wc * 64 + n * 16 + ccol;
        if (labi[i] != labj[j]) {
          hs += fmaxf(0.5f - acc[m][n][r], 0.f);
        }
      }
    }
  }
  #pragma unroll
  for (int off = 32; off; off >>= 1) hs += __shfl_down(hs, off, 64);
  if (lane == 0) rsum[wave] = hs;
  __syncthreads();
  if (tid == 0) {
    float s = 0.f;
    #pragma unroll
    for (int w = 0; w < 8; ++w) s += rsum[w];
    if (ti != tj) s *= 2.f;
    adv_val[bid0] = s;
  }
}

// ---------------- finalize (unchanged from R9) ----------------
__global__ __launch_bounds__(1024) void finalize_kernel(
    const float* __restrict__ intra_val, const float* __restrict__ adv_val,
    const int* __restrict__ hist, float* __restrict__ out) {
  __shared__ float rsi[16], rsa[16];
  __shared__ long long rsq[16];
  const int tid = threadIdx.x;
  const int wave = tid >> 6, lane = tid & 63;

  float si = 0.f;
  for (int i = tid; i < NROWS; i += 1024) si += intra_val[i];
  float sa = 0.f;
  if (tid < NTRI) sa = adv_val[tid];
  long long sq = 0;
  if (tid < NCLS) { long long h = hist[tid]; sq = h * h; }

  #pragma unroll
  for (int off = 32; off; off >>= 1) {
    si += __shfl_down(si, off, 64);
    sa += __shfl_down(sa, off, 64);
    sq += __shfl_down(sq, off, 64);
  }
  if (lane == 0) { rsi[wave] = si; rsa[wave] = sa; rsq[wave] = sq; }
  __syncthreads();
  if (tid == 0) {
    float SI = 0.f, SA = 0.f; long long SQ = 0;
    for (int w = 0; w < 16; ++w) { SI += rsi[w]; SA += rsa[w]; SQ += rsq[w]; }
    long long npairs = (long long)NROWS * NROWS - SQ;
    if (npairs < 1) npairs = 1;
    out[0] = SI / (float)NROWS + 0.5f * (SA / (float)npairs);
  }
}

__global__ void sentinel_kernel(float* out) {
  if (threadIdx.x == 0 && blockIdx.x == 0) out[0] = -1.0f;
}

extern "C" void kernel_launch(void* const* d_in, const int* in_sizes, int n_in,
                              void* d_out, int out_size, void* d_ws, size_t ws_size,
                              hipStream_t stream) {
  const float* feat    = (const float*)d_in[0];
  const int*   labels  = (const int*)d_in[1];
  const float* centers = (const float*)d_in[2];
  float* out = (float*)d_out;

  if (ws_size < (size_t)WS_NEEDED) {
    sentinel_kernel<<<1, 64, 0, stream>>>(out);
    return;
  }

  char* ws = (char*)d_ws;
  unsigned short* fhat = (unsigned short*)(ws + FHAT_OFF);
  float* intra_val = (float*)(ws + INTRA_OFF);
  float* adv_val   = (float*)(ws + ADV_OFF);
  int*   hist      = (int*)(ws + HIST_OFF);

  hipMemsetAsync(ws + HIST_OFF, 0, NCLS * 4, stream);

  prep_kernel<<<NROWS / 4, 256, 0, stream>>>(feat, labels, centers, fhat,
                                             intra_val, hist);
  gemm_hinge_kernel<<<NTRI, 512, 0, stream>>>(fhat, labels, adv_val);
  finalize_kernel<<<1, 1024, 0, stream>>>(intra_val, adv_val, hist, out);
}

// Round 13
// 170.950 us; speedup vs baseline: 1.9108x; 1.0646x over previous
//
#include <hip/hip_runtime.h>

// BDC loss, round 13 (= round-12 kernel, never ran due to infra; re-audited).
//   prep    (2048 blocks, 1 wave/row): norms+intra+fhat
//   gemm512 (512 full 256x256 tiles = 2 clean rounds): counted-vmcnt dbuf
//           + XOR swizzle + setprio
//   gemmQ   (64 quarter 128x128 tiles from the 16 leftover tris)
//   final   (1 block)
// R11: conflicts 0, MfmaUtil 27.3%, 104us; tail = 528/(3*256) = 69% packing.
// This round: 512+64 split -> 92% packing; setprio (T5).

typedef __attribute__((ext_vector_type(8))) short bf16x8;
typedef __attribute__((ext_vector_type(4))) float f32x4;

#define NROWS 8192
#define NDIM  1024
#define NCLS  1000
#define NTILE 32
#define NADV  576                // 512 fulls + 64 quarters

#define FHAT_OFF  0                          // 16777216 B
#define INTRA_OFF 16777216                   // 8192 f32
#define ADV_OFF   (INTRA_OFF + NROWS * 4)    // 576 f32
#define HIST_OFF  (ADV_OFF + NADV * 4)       // 1000 int
#define WS_NEEDED (HIST_OFF + NCLS * 4)

static __device__ __forceinline__ unsigned short f2bf(float x) {
  unsigned u = __float_as_uint(x);
  u += 0x7fffu + ((u >> 16) & 1u);
  return (unsigned short)(u >> 16);
}

// ---------------- prep (unchanged from R9/R11) ----------------
__global__ __launch_bounds__(256) void prep_kernel(
    const float* __restrict__ feat, const int* __restrict__ labels,
    const float* __restrict__ centers, unsigned short* __restrict__ fhat,
    float* __restrict__ intra_val, int* __restrict__ hist) {
  const int tid = threadIdx.x, wave = tid >> 6, lane = tid & 63;
  const int row = blockIdx.x * 4 + wave;

  const float4* fr = (const float4*)(feat + (size_t)row * NDIM);
  const int lab = labels[row];
  const float4* cr = (const float4*)(centers + (size_t)lab * NDIM);

  float4 f[4], c[4];
  #pragma unroll
  for (int j = 0; j < 4; ++j) { f[j] = fr[lane + j * 64]; c[j] = cr[lane + j * 64]; }

  float ff = 0.f, fc = 0.f, cc = 0.f, se = 0.f;
  #pragma unroll
  for (int j = 0; j < 4; ++j) {
    ff += f[j].x*f[j].x + f[j].y*f[j].y + f[j].z*f[j].z + f[j].w*f[j].w;
    fc += f[j].x*c[j].x + f[j].y*c[j].y + f[j].z*c[j].z + f[j].w*c[j].w;
    cc += c[j].x*c[j].x + c[j].y*c[j].y + c[j].z*c[j].z + c[j].w*c[j].w;
    float dx = f[j].x-c[j].x, dy = f[j].y-c[j].y, dz = f[j].z-c[j].z, dw = f[j].w-c[j].w;
    se += dx*dx + dy*dy + dz*dz + dw*dw;
  }
  #pragma unroll
  for (int off = 1; off < 64; off <<= 1) {
    ff += __shfl_xor(ff, off, 64);
    fc += __shfl_xor(fc, off, 64);
    cc += __shfl_xor(cc, off, 64);
    se += __shfl_xor(se, off, 64);
  }
  const float fn = fmaxf(sqrtf(ff), 1e-8f);
  const float cn = fmaxf(sqrtf(cc), 1e-8f);
  const float inv = 1.0f / fn;
  if (lane == 0) {
    intra_val[row] = se * expf(-(fc / (fn * cn)));
    atomicAdd(&hist[lab], 1);
  }
  ushort4* orow = (ushort4*)(fhat + (size_t)row * NDIM);
  #pragma unroll
  for (int j = 0; j < 4; ++j) {
    ushort4 o;
    o.x = f2bf(f[j].x * inv); o.y = f2bf(f[j].y * inv);
    o.z = f2bf(f[j].z * inv); o.w = f2bf(f[j].w * inv);
    orow[lane + j * 64] = o;
  }
}

#define CUMUL(r) ((r) * NTILE - (r) * ((r) - 1) / 2)

#define TRI_DECODE(BID, TI, TJ)                                               \
  const float nf = (float)NTILE + 0.5f;                                       \
  int TI = (int)floorf(nf - sqrtf(nf * nf - 2.0f * (float)(BID)));            \
  while (TI > 0 && (BID) < CUMUL(TI)) --TI;                                   \
  while ((BID) >= CUMUL(TI + 1)) ++TI;                                        \
  const int TJ = TI + ((BID) - CUMUL(TI));

// ---------------- full-tile GEMM: 512 blocks, 256x256 ----------------
__global__ __launch_bounds__(512) void gemm_full_kernel(
    const unsigned short* __restrict__ fhat, const int* __restrict__ labels,
    float* __restrict__ adv_val) {
  const int f = blockIdx.x;                       // 0..511
  const int bid = (f & 7) * 66 + (f >> 3);        // XCD chunk, offs 0..63
  TRI_DECODE(bid, ti, tj);

  __shared__ __align__(16) unsigned short Al[2][256 * 64];
  __shared__ __align__(16) unsigned short Bl[2][256 * 64];
  __shared__ int labi[256], labj[256];
  __shared__ float rsum[8];

  const int tid  = threadIdx.x;
  const int wave = tid >> 6, lane = tid & 63;
  const int wr = wave >> 2, wc = wave & 3;        // 2x4 -> 128x64 per wave

  if (tid < 256) labi[tid] = labels[ti * 256 + tid];
  else           labj[tid - 256] = labels[tj * 256 + (tid - 256)];

  f32x4 acc[8][4] = {};

  const int l8 = lane >> 3;
  const int sl = ((lane & 7) ^ l8) * 8;           // pre-swizzled source slot
  const unsigned short* aS = fhat + (size_t)(ti * 256 + wave * 32 + l8) * NDIM + sl;
  const unsigned short* bS = fhat + (size_t)(tj * 256 + wave * 32 + l8) * NDIM + sl;

#define STAGE(BUF, K0)                                                        \
  do {                                                                        \
    _Pragma("unroll")                                                         \
    for (int j = 0; j < 4; ++j) {                                             \
      __builtin_amdgcn_global_load_lds(                                       \
          (const __attribute__((address_space(1))) void*)(aS + (K0) + j * 8 * NDIM), \
          (__attribute__((address_space(3))) void*)&Al[BUF][(wave * 4 + j) * 512],   \
          16, 0, 0);                                                          \
      __builtin_amdgcn_global_load_lds(                                       \
          (const __attribute__((address_space(1))) void*)(bS + (K0) + j * 8 * NDIM), \
          (__attribute__((address_space(3))) void*)&Bl[BUF][(wave * 4 + j) * 512],   \
          16, 0, 0);                                                          \
    }                                                                         \
  } while (0)

  const int lr = lane & 15;
  const int hk = (lane >> 4) * 8;
  const int xr = (lr & 7) << 3;

#define COMPUTE(BUF)                                                          \
  do {                                                                        \
    __builtin_amdgcn_s_setprio(1);                                            \
    _Pragma("unroll")                                                         \
    for (int kk = 0; kk < 2; ++kk) {                                          \
      const int lx = (kk * 32 + hk) ^ xr;                                     \
      bf16x8 a[8], b[4];                                                      \
      _Pragma("unroll")                                                       \
      for (int m = 0; m < 8; ++m)                                             \
        a[m] = *(const bf16x8*)&Al[BUF][(wr * 128 + m * 16 + lr) * 64 + lx];  \
      _Pragma("unroll")                                                       \
      for (int n = 0; n < 4; ++n)                                             \
        b[n] = *(const bf16x8*)&Bl[BUF][(wc * 64 + n * 16 + lr) * 64 + lx];   \
      _Pragma("unroll")                                                       \
      for (int m = 0; m < 8; ++m)                                             \
        _Pragma("unroll")                                                     \
        for (int n = 0; n < 4; ++n)                                           \
          acc[m][n] = __builtin_amdgcn_mfma_f32_16x16x32_bf16(                \
              a[m], b[n], acc[m][n], 0, 0, 0);                                \
    }                                                                         \
    __builtin_amdgcn_s_setprio(0);                                            \
  } while (0)

#define KITER(T, CBUF)                                                        \
  do {                                                                        \
    STAGE(CBUF ^ 1, ((T) + 1) * 64);                                          \
    __builtin_amdgcn_sched_barrier(0);                                        \
    asm volatile("s_waitcnt vmcnt(8)" ::: "memory");                          \
    __builtin_amdgcn_sched_barrier(0);                                        \
    __builtin_amdgcn_s_barrier();                                             \
    __builtin_amdgcn_sched_barrier(0);                                        \
    COMPUTE(CBUF);                                                            \
    asm volatile("s_waitcnt lgkmcnt(0)" ::: "memory");                        \
    __builtin_amdgcn_sched_barrier(0);                                        \
    __builtin_amdgcn_s_barrier();                                             \
    __builtin_amdgcn_sched_barrier(0);                                        \
  } while (0)

  STAGE(0, 0);
  #pragma unroll 1
  for (int t2 = 0; t2 < 7; ++t2) {
    KITER(2 * t2, 0);
    KITER(2 * t2 + 1, 1);
  }
  KITER(14, 0);
  asm volatile("s_waitcnt vmcnt(0)" ::: "memory");
  __builtin_amdgcn_sched_barrier(0);
  __builtin_amdgcn_s_barrier();
  __builtin_amdgcn_sched_barrier(0);
  COMPUTE(1);

#undef KITER
#undef STAGE
#undef COMPUTE

  float hs = 0.f;
  const int crow = (lane >> 4) * 4;
  const int ccol = lane & 15;
  #pragma unroll
  for (int m = 0; m < 8; ++m)
    #pragma unroll
    for (int n = 0; n < 4; ++n)
      #pragma unroll
      for (int r = 0; r < 4; ++r) {
        const int i = wr * 128 + m * 16 + crow + r;
        const int j = wc * 64 + n * 16 + ccol;
        if (labi[i] != labj[j]) hs += fmaxf(0.5f - acc[m][n][r], 0.f);
      }
  #pragma unroll
  for (int off = 32; off; off >>= 1) hs += __shfl_down(hs, off, 64);
  if (lane == 0) rsum[wave] = hs;
  __syncthreads();
  if (tid == 0) {
    float s = 0.f;
    #pragma unroll
    for (int w = 0; w < 8; ++w) s += rsum[w];
    if (ti != tj) s *= 2.f;
    adv_val[f] = s;
  }
}

// ---------------- quarter-tile GEMM: 64 blocks, 128x128 ----------------
// parents: tri = (p>>1)*66 + 64 + (p&1), p = bid>>2 in [0,16)
__global__ __launch_bounds__(512) void gemm_quarter_kernel(
    const unsigned short* __restrict__ fhat, const int* __restrict__ labels,
    float* __restrict__ adv_val) {
  const int bq = blockIdx.x;                      // 0..63
  const int p = bq >> 2;
  const int bid = (p >> 1) * 66 + 64 + (p & 1);   // leftover tris
  const int qm = (bq >> 1) & 1, qn = bq & 1;
  TRI_DECODE(bid, ti, tj);
  const int row0 = ti * 256 + qm * 128;
  const int col0 = tj * 256 + qn * 128;

  __shared__ __align__(16) unsigned short Al[2][128 * 64];
  __shared__ __align__(16) unsigned short Bl[2][128 * 64];
  __shared__ int labi[128], labj[128];
  __shared__ float rsum[8];

  const int tid  = threadIdx.x;
  const int wave = tid >> 6, lane = tid & 63;
  const int wr = wave >> 2, wc = wave & 3;        // 2x4 -> 64x32 per wave

  if (tid < 128) labi[tid] = labels[row0 + tid];
  else if (tid < 256) labj[tid - 128] = labels[col0 + (tid - 128)];

  f32x4 acc[4][2] = {};

  const int l8 = lane >> 3;
  const int sl = ((lane & 7) ^ l8) * 8;
  const unsigned short* aS = fhat + (size_t)(row0 + wave * 16 + l8) * NDIM + sl;
  const unsigned short* bS = fhat + (size_t)(col0 + wave * 16 + l8) * NDIM + sl;

#define STAGE(BUF, K0)                                                        \
  do {                                                                        \
    _Pragma("unroll")                                                         \
    for (int j = 0; j < 2; ++j) {                                             \
      __builtin_amdgcn_global_load_lds(                                       \
          (const __attribute__((address_space(1))) void*)(aS + (K0) + j * 8 * NDIM), \
          (__attribute__((address_space(3))) void*)&Al[BUF][(wave * 2 + j) * 512],   \
          16, 0, 0);                                                          \
      __builtin_amdgcn_global_load_lds(                                       \
          (const __attribute__((address_space(1))) void*)(bS + (K0) + j * 8 * NDIM), \
          (__attribute__((address_space(3))) void*)&Bl[BUF][(wave * 2 + j) * 512],   \
          16, 0, 0);                                                          \
    }                                                                         \
  } while (0)

  const int lr = lane & 15;
  const int hk = (lane >> 4) * 8;
  const int xr = (lr & 7) << 3;

#define COMPUTE(BUF)                                                          \
  do {                                                                        \
    __builtin_amdgcn_s_setprio(1);                                            \
    _Pragma("unroll")                                                         \
    for (int kk = 0; kk < 2; ++kk) {                                          \
      const int lx = (kk * 32 + hk) ^ xr;                                     \
      bf16x8 a[4], b[2];                                                      \
      _Pragma("unroll")                                                       \
      for (int m = 0; m < 4; ++m)                                             \
        a[m] = *(const bf16x8*)&Al[BUF][(wr * 64 + m * 16 + lr) * 64 + lx];   \
      _Pragma("unroll")                                                       \
      for (int n = 0; n < 2; ++n)                                             \
        b[n] = *(const bf16x8*)&Bl[BUF][(wc * 32 + n * 16 + lr) * 64 + lx];   \
      _Pragma("unroll")                                                       \
      for (int m = 0; m < 4; ++m)                                             \
        _Pragma("unroll")                                                     \
        for (int n = 0; n < 2; ++n)                                           \
          acc[m][n] = __builtin_amdgcn_mfma_f32_16x16x32_bf16(                \
              a[m], b[n], acc[m][n], 0, 0, 0);                                \
    }                                                                         \
    __builtin_amdgcn_s_setprio(0);                                            \
  } while (0)

#define KITER(T, CBUF)                                                        \
  do {                                                                        \
    STAGE(CBUF ^ 1, ((T) + 1) * 64);                                          \
    __builtin_amdgcn_sched_barrier(0);                                        \
    asm volatile("s_waitcnt vmcnt(4)" ::: "memory");                          \
    __builtin_amdgcn_sched_barrier(0);                                        \
    __builtin_amdgcn_s_barrier();                                             \
    __builtin_amdgcn_sched_barrier(0);                                        \
    COMPUTE(CBUF);                                                            \
    asm volatile("s_waitcnt lgkmcnt(0)" ::: "memory");                        \
    __builtin_amdgcn_sched_barrier(0);                                        \
    __builtin_amdgcn_s_barrier();                                             \
    __builtin_amdgcn_sched_barrier(0);                                        \
  } while (0)

  STAGE(0, 0);
  #pragma unroll 1
  for (int t2 = 0; t2 < 7; ++t2) {
    KITER(2 * t2, 0);
    KITER(2 * t2 + 1, 1);
  }
  KITER(14, 0);
  asm volatile("s_waitcnt vmcnt(0)" ::: "memory");
  __builtin_amdgcn_sched_barrier(0);
  __builtin_amdgcn_s_barrier();
  __builtin_amdgcn_sched_barrier(0);
  COMPUTE(1);

#undef KITER
#undef STAGE
#undef COMPUTE

  float hs = 0.f;
  const int crow = (lane >> 4) * 4;
  const int ccol = lane & 15;
  #pragma unroll
  for (int m = 0; m < 4; ++m)
    #pragma unroll
    for (int n = 0; n < 2; ++n)
      #pragma unroll
      for (int r = 0; r < 4; ++r) {
        const int i = wr * 64 + m * 16 + crow + r;
        const int j = wc * 32 + n * 16 + ccol;
        if (labi[i] != labj[j]) hs += fmaxf(0.5f - acc[m][n][r], 0.f);
      }
  #pragma unroll
  for (int off = 32; off; off >>= 1) hs += __shfl_down(hs, off, 64);
  if (lane == 0) rsum[wave] = hs;
  __syncthreads();
  if (tid == 0) {
    float s = 0.f;
    #pragma unroll
    for (int w = 0; w < 8; ++w) s += rsum[w];
    if (ti != tj) s *= 2.f;     // mirrors of diag-parent quarters both computed
    adv_val[512 + bq] = s;
  }
}

// ---------------- finalize ----------------
__global__ __launch_bounds__(1024) void finalize_kernel(
    const float* __restrict__ intra_val, const float* __restrict__ adv_val,
    const int* __restrict__ hist, float* __restrict__ out) {
  __shared__ float rsi[16], rsa[16];
  __shared__ long long rsq[16];
  const int tid = threadIdx.x;
  const int wave = tid >> 6, lane = tid & 63;

  float si = 0.f;
  for (int i = tid; i < NROWS; i += 1024) si += intra_val[i];
  float sa = 0.f;
  if (tid < NADV) sa = adv_val[tid];
  long long sq = 0;
  if (tid < NCLS) { long long h = hist[tid]; sq = h * h; }

  #pragma unroll
  for (int off = 32; off; off >>= 1) {
    si += __shfl_down(si, off, 64);
    sa += __shfl_down(sa, off, 64);
    sq += __shfl_down(sq, off, 64);
  }
  if (lane == 0) { rsi[wave] = si; rsa[wave] = sa; rsq[wave] = sq; }
  __syncthreads();
  if (tid == 0) {
    float SI = 0.f, SA = 0.f; long long SQ = 0;
    for (int w = 0; w < 16; ++w) { SI += rsi[w]; SA += rsa[w]; SQ += rsq[w]; }
    long long npairs = (long long)NROWS * NROWS - SQ;
    if (npairs < 1) npairs = 1;
    out[0] = SI / (float)NROWS + 0.5f * (SA / (float)npairs);
  }
}

__global__ void sentinel_kernel(float* out) {
  if (threadIdx.x == 0 && blockIdx.x == 0) out[0] = -1.0f;
}

extern "C" void kernel_launch(void* const* d_in, const int* in_sizes, int n_in,
                              void* d_out, int out_size, void* d_ws, size_t ws_size,
                              hipStream_t stream) {
  const float* feat    = (const float*)d_in[0];
  const int*   labels  = (const int*)d_in[1];
  const float* centers = (const float*)d_in[2];
  float* out = (float*)d_out;

  if (ws_size < (size_t)WS_NEEDED) {
    sentinel_kernel<<<1, 64, 0, stream>>>(out);
    return;
  }

  char* ws = (char*)d_ws;
  unsigned short* fhat = (unsigned short*)(ws + FHAT_OFF);
  float* intra_val = (float*)(ws + INTRA_OFF);
  float* adv_val   = (float*)(ws + ADV_OFF);
  int*   hist      = (int*)(ws + HIST_OFF);

  hipMemsetAsync(ws + HIST_OFF, 0, NCLS * 4, stream);

  prep_kernel<<<NROWS / 4, 256, 0, stream>>>(feat, labels, centers, fhat,
                                             intra_val, hist);
  gemm_full_kernel<<<512, 512, 0, stream>>>(fhat, labels, adv_val);
  gemm_quarter_kernel<<<64, 512, 0, stream>>>(fhat, labels, adv_val);
  finalize_kernel<<<1, 1024, 0, stream>>>(intra_val, adv_val, hist, out);
}